// Round 1
// 224.866 us; speedup vs baseline: 1.1846x; 1.1846x over previous
//
#include <hip/hip_runtime.h>
#include <hip/hip_bf16.h>
#include <stdint.h>

// EMASpitDelta: B=128, L=4096, H=64, V=64, HALF=32, ALPHA=0.95
// V=64 -> token pipeline collapses to a 64-entry table, AND every inner
// product the backward scan needs is an entry of the 64x64 Gram table
// G[v][v'] = k_v . k_v'. Per (b,mat) we run ONE wave with lane = token id
// holding y[v] = k_v . z  (z = implicit suffix state):
//   step t (descending): sy = y[v_t] (v_readlane, v_t uniform)
//                        d  = b_t*sy ; dacc[v_t] += d   (lane v_t only)
//                        y[v] -= d * G[v][v_t]          (1 LDS row + 1 fmac)
// z itself never materializes; r = H . dacc at the end (h table shared
// across steps too). This deletes the old P-matrix pipeline entirely
// (chunk_scan_p 106us + fold_z + suffix_scan, 33.5MB Pbuf traffic).
// Critical chain = readlane -> fmac (G row pre-scaled by -b_t; since
// G[v][v]~=1 the diagonal element IS -b_t, giving dacc for free).

#define BETA 0.05f
#define NB 128
#define NL 4096
#define NSTEPS 4095

// fp32 arena offsets (floats)
#define A_EMBED 0
#define A_W1    4096
#define A_B1    12288
#define A_W2    12416
#define A_B2    20608
#define A_GAMMA 20672
#define A_BETA  20736
#define A_WSM   20800
#define A_BS    22848
#define A_WEM   22880
#define A_BE    24928
#define A_WRP   24960
#define A_BRP   29056
#define A_WOUT  29120
#define A_BOUT  33216
#define A_TOTAL 33280

struct Ptrs { const void* p[15]; };

__device__ inline float readlane_f(float v, int l) {
    return __int_as_float(__builtin_amdgcn_readlane(__float_as_int(v), l));
}

// ---------------- Kernel 0: detect dtype + convert to fp32 arena ----------
__global__ __launch_bounds__(256) void convert_inputs(Ptrs ps, float* __restrict__ arena)
{
    const int sizes[15] = {4096, 8192, 128, 8192, 64, 64, 64, 2048, 32, 2048, 32, 4096, 64, 4096, 64};
    const int offs[15] = {A_EMBED, A_W1, A_B1, A_W2, A_B2, A_GAMMA, A_BETA,
                          A_WSM, A_BS, A_WEM, A_BE, A_WRP, A_BRP, A_WOUT, A_BOUT};
    uint32_t g0 = *(const uint32_t*)ps.p[5];
    int isbf = (g0 == 0x3F803F80u) ? 1 : 0;
    int t = blockIdx.x;
    const void* src = ps.p[t];
    float* dst = arena + offs[t];
    int n = sizes[t];
    if (isbf) {
        const __hip_bfloat16* s = (const __hip_bfloat16*)src;
        for (int i = threadIdx.x; i < n; i += 256) dst[i] = __bfloat162float(s[i]);
    } else {
        const float* s = (const float*)src;
        for (int i = threadIdx.x; i < n; i += 256) dst[i] = s[i];
    }
}

// ---------------- Kernel 1: per-token-value tables ----------------
// grid 64 (token v), block 64 (feature j). tbl (f32):
// [0..2047]=hs, [2048..4095]=ks(norm), [4096..6143]=he, [6144..8191]=ke
__global__ __launch_bounds__(64, 2) void build_tables(const float* __restrict__ A,
                                                      float* __restrict__ tbl)
{
    int v = blockIdx.x;
    int j = threadIdx.x;
    __shared__ float h0s[64];
    __shared__ float act[128];
    __shared__ float hrow[64];

    float h0 = A[A_EMBED + v * 64 + j];
    h0s[j] = h0;
    __syncthreads();

    float za = A[A_B1 + j];
    float zb = A[A_B1 + j + 64];
    for (int k = 0; k < 64; ++k) {
        float hk = h0s[k];
        za = fmaf(hk, A[A_W1 + k * 128 + j], za);
        zb = fmaf(hk, A[A_W1 + k * 128 + j + 64], zb);
    }
    act[j] = fmaxf(za, 0.0f);
    act[j + 64] = fmaxf(zb, 0.0f);
    __syncthreads();

    float ff = A[A_B2 + j];
    for (int k = 0; k < 128; ++k)
        ff = fmaf(act[k], A[A_W2 + k * 64 + j], ff);
    float x = h0 + ff;

    float s = x;
    for (int off = 32; off >= 1; off >>= 1) s += __shfl_xor(s, off, 64);
    float mu = s * (1.0f / 64.0f);
    float d = x - mu;
    float s2 = d * d;
    for (int off = 32; off >= 1; off >>= 1) s2 += __shfl_xor(s2, off, 64);
    float var = s2 * (1.0f / 64.0f);
    float h = d / sqrtf(var + 1e-5f) * A[A_GAMMA + j] + A[A_BETA + j];
    hrow[j] = h;
    __syncthreads();

    if (j < 32) {
        float sv = A[A_BS + j];
        for (int k = 0; k < 64; ++k)
            sv = fmaf(hrow[k], A[A_WSM + k * 32 + j], sv);
        float n2 = sv * sv;
        for (int off = 16; off >= 1; off >>= 1) n2 += __shfl_xor(n2, off, 64);
        float nrm = fmaxf(sqrtf(n2), 1e-12f);
        tbl[v * 32 + j] = sv;
        tbl[2048 + v * 32 + j] = sv / nrm;
    } else {
        int jj = j - 32;
        float ev = A[A_BE + jj];
        for (int k = 0; k < 64; ++k)
            ev = fmaf(hrow[k], A[A_WEM + k * 32 + jj], ev);
        float n2 = ev * ev;
        for (int off = 16; off >= 1; off >>= 1) n2 += __shfl_xor(n2, off, 64);
        float nrm = fmaxf(sqrtf(n2), 1e-12f);
        tbl[4096 + v * 32 + jj] = ev;
        tbl[6144 + v * 32 + jj] = ev / nrm;
    }
}

// ---------------- Kernel 1b: Gram tables G[mat][vt][v] = k_vt . k_v ------
// grid 128 = (mat,vt), block 64 (lane = v). K staged in LDS padded to 33
// (kl[j] at lane*33+j -> bank (lane+j)%32, 2/bank, conflict-free).
__global__ __launch_bounds__(64, 2) void gram_tables(const float* __restrict__ tbl,
                                                     float* __restrict__ G)
{
    int mat = blockIdx.x >> 6, vt = blockIdx.x & 63;
    int lane = threadIdx.x;
    __shared__ float K[64 * 33];
    const float* ks = tbl + 2048 + mat * 4096;
    for (int i = lane; i < 2048; i += 64)
        K[(i >> 5) * 33 + (i & 31)] = ks[i];
    __syncthreads();
    const float* kr = K + vt * 33;
    const float* kl = K + lane * 33;
    float s = 0.0f;
#pragma unroll
    for (int j = 0; j < 32; ++j) s = fmaf(kr[j], kl[j], s);
    G[(size_t)(mat * 64 + vt) * 64 + lane] = s;
}

// ---------------- Kernel 2: the whole backward scan, Gram-table form ------
// grid = NB*2 (one wave per (b,mat)), block 64, lane = token id.
// 64 groups of 64 steps, descending. Per group: lane l prefetches token
// t=g*64+l and its -b_t; phase 1 loads the 64 G rows (uniform row ->
// lane-contiguous, conflict-free) scaled by -b_t into gv[64] (static
// indices, stays in VGPRs); phase 2 runs the 2-op/step readlane->fmac
// chain. dacc accumulated negated via the diagonal trick (gv[s] at lane
// v_t equals -b_t since |k|^2 ~= 1).
__global__ __launch_bounds__(64, 1) void ema_scan(
    const int* __restrict__ seq, const float* __restrict__ tbl,
    const float* __restrict__ G, float* __restrict__ rvbuf)
{
    __shared__ float Gl[64 * 64];
    __shared__ float da[64];

    int bm = blockIdx.x;
    int b = bm >> 1, mat = bm & 1;
    int lane = threadIdx.x;

    const float* gs = G + (size_t)mat * 4096;
    for (int i = lane; i < 4096; i += 64) Gl[i] = gs[i];
    const int* sb = seq + (size_t)b * NL;
    int vlast = sb[NL - 1];
    int tok = sb[63 * 64 + lane];          // prefetch group 63
    __syncthreads();

    // y[v] = k_v . q ; q = ks[vlast]  =>  y = G[vlast][lane]
    float y = Gl[vlast * 64 + lane];
    float daccn = 0.0f;
    const float bstep = BETA * (1.0f / 4096.0f);

    for (int g = 63; g >= 0; --g) {
        int tokc = tok;
        if (g > 0) tok = sb[(g - 1) * 64 + lane];   // prefetch next group
        // -b_t for t = g*64+lane (t=4095 masked to 0)
        float t1 = (float)(g * 64 + lane + 1);
        float bneg = mat ? (-bstep * t1) : (-BETA);
        if (g == 63 && lane == 63) bneg = 0.0f;

        float gv[64];
#pragma unroll
        for (int s = 63; s >= 0; --s) {
            int svt = __builtin_amdgcn_readlane(tokc, s);
            float sbn = readlane_f(bneg, s);
            gv[s] = Gl[svt * 64 + lane] * sbn;     // -b_t * G[v_t][lane]
        }
#pragma unroll
        for (int s = 63; s >= 0; --s) {
            int svt = __builtin_amdgcn_readlane(tokc, s);
            float sy = readlane_f(y, svt);          // k_{v_t} . z   (chain)
            y = fmaf(sy, gv[s], y);                 // y -= d*G row  (chain)
            float ysel = (lane == svt) ? sy : 0.0f; // off-chain
            daccn = fmaf(ysel, gv[s], daccn);       // daccn += -b_t*sy @lane v_t
        }
    }

    da[lane] = -daccn;
    __syncthreads();

    if (lane < 32) {
        const float* h = tbl + mat * 4096;          // hs or he (unnormalized)
        float r = 0.0f;
        for (int v = 0; v < 64; ++v)
            r = fmaf(da[v], h[v * 32 + lane], r);
        rvbuf[(size_t)bm * 32 + lane] = r;
    }
}

// ---------------- Kernel 5: readout projections ---------------------------
__global__ __launch_bounds__(64, 2) void reduce_readout(
    const float* __restrict__ rvbuf, const float* __restrict__ A,
    const void* ln_g, void* __restrict__ outv)
{
    __shared__ float rv[64];
    __shared__ float o1s[64];
    int b = blockIdx.x;
    int tid = threadIdx.x;

    rv[tid] = rvbuf[b * 64 + tid];   // [rs | re]
    __syncthreads();
    float o = A[A_BRP + tid];
    for (int i = 0; i < 64; ++i)
        o = fmaf(rv[i], A[A_WRP + i * 64 + tid], o);
    o1s[tid] = o;
    __syncthreads();
    float o2 = A[A_BOUT + tid];
    for (int i = 0; i < 64; ++i)
        o2 = fmaf(o1s[i], A[A_WOUT + i * 64 + tid], o2);
    int isbf = (*(const uint32_t*)ln_g == 0x3F803F80u) ? 1 : 0;
    if (isbf)
        ((__hip_bfloat16*)outv)[b * 64 + tid] = __float2bfloat16(o2);
    else
        ((float*)outv)[b * 64 + tid] = o2;
}

extern "C" void kernel_launch(void* const* d_in, const int* in_sizes, int n_in,
                              void* d_out, int out_size, void* d_ws, size_t ws_size,
                              hipStream_t stream) {
    const int* seq = (const int*)d_in[0];
    Ptrs ps;
    for (int i = 0; i < 15; ++i) ps.p[i] = d_in[i + 1];
    const void* ln_g = d_in[6];

    // ws (floats): arena[33280] | tbl[8192] | G[8192] | rvbuf[8192]
    float* arena = (float*)d_ws;
    float* tbl = arena + A_TOTAL;
    float* G = tbl + 8192;
    float* rvbuf = G + 8192;

    convert_inputs<<<15, 256, 0, stream>>>(ps, arena);
    build_tables<<<64, 64, 0, stream>>>(arena, tbl);
    gram_tables<<<128, 64, 0, stream>>>(tbl, G);
    ema_scan<<<NB * 2, 64, 0, stream>>>(seq, tbl, G, rvbuf);
    reduce_readout<<<NB, 64, 0, stream>>>(rvbuf, arena, ln_g, d_out);
}